// Round 4
// baseline (775.227 us; speedup 1.0000x reference)
//
#include <hip/hip_runtime.h>
#include <hip/hip_bf16.h>
#include <stdint.h>
#include <stddef.h>

typedef __attribute__((ext_vector_type(8))) _Float16 f16x8;
typedef __attribute__((ext_vector_type(4))) float f32x4;

#define B_ROWS 1024
#define ND 256

// ---------------------------------------------------------------------------
// Kernel 1: convert W (fp32 [K][256]) -> fp16 RTN, chunked [c][256][32] so
// MFMA B-fragments are contiguous 16B runs. Fully-coalesced global reads.
// ---------------------------------------------------------------------------
struct ConvArgs {
  const float* W[4];
  unsigned short* dst[4];
  int K[4];
  int chBase[4];
};

__global__ void conv_w_kernel(ConvArgs a){
  int cb = blockIdx.x;
  int w = 0;
  if (cb >= a.chBase[1]) w = 1;
  if (cb >= a.chBase[2]) w = 2;
  if (cb >= a.chBase[3]) w = 3;
  int c = cb - a.chBase[w];
  __shared__ float tile[32][257];
  const float* Wp = a.W[w];
  int K = a.K[w];
  int t = threadIdx.x;
  // fully coalesced: 2048 float4 cover the 32x256 block; lane-contiguous 16B
  const float* src = Wp + (size_t)c * 32 * ND;
  bool full = (c * 32 + 32 <= K);
  #pragma unroll
  for (int j = 0; j < 8; ++j){
    int idx = j * 256 + t;          // float4 index in block
    int row = idx >> 6;             // 0..31
    int col = (idx & 63) * 4;
    float4 v;
    if (full || (c * 32 + row < K)) v = *(const float4*)(src + (size_t)idx * 4);
    else { v.x = v.y = v.z = v.w = 0.f; }
    tile[row][col+0] = v.x; tile[row][col+1] = v.y;
    tile[row][col+2] = v.z; tile[row][col+3] = v.w;
  }
  __syncthreads();
  int n = t;
  union { unsigned short s[32]; uint4 v[4]; } pk;
  #pragma unroll
  for (int k = 0; k < 32; ++k){
    _Float16 h = (_Float16)tile[k][n];                  // RTN
    pk.s[k] = *(unsigned short*)&h;
  }
  unsigned short* d = a.dst[w] + ((size_t)c * ND + n) * 32;
  #pragma unroll
  for (int q = 0; q < 4; ++q) *(uint4*)(d + q*8) = pk.v[q];  // 64B/lane contiguous
}

// ---------------------------------------------------------------------------
// Kernel 2: init the 10 embedding buffers with biases (GEMM atomics accumulate).
// ---------------------------------------------------------------------------
struct BiasArgs { float* emb; const float* b[10]; };

__global__ void bias_init_kernel(BiasArgs a){
  int idx = blockIdx.x * blockDim.x + threadIdx.x;  // one float4 per thread
  int g  = idx >> 16;          // 65536 float4 per (1024x256) buffer
  int wi = idx & 65535;
  int n4 = (wi & 63) * 4;
  const float* bp = a.b[g];
  float4 v; v.x = bp[n4]; v.y = bp[n4+1]; v.z = bp[n4+2]; v.w = bp[n4+3];
  *(float4*)(a.emb + (size_t)idx * 4) = v;
}

// ---------------------------------------------------------------------------
// Kernel 3: barrier-free 2-term fp16-split MFMA GEMM.
// C[g] += X[g] @ fp16(W[g]).  A-fragments loaded DIRECTLY from global
// (8 contiguous floats per lane = the exact 16x16x32 A layout), converted
// fp32->fp16 hi/lo in-register.  No LDS, no __syncthreads -> no vmcnt(0)
// drains; latency hidden by TLP (16 waves/CU).
// ---------------------------------------------------------------------------
struct GemmArgs {
  const float* X[10];
  const unsigned short* Wh[10];
  float* C[10];
  int K[10];
  int nch[10];
  int ksplit[10];
  int wgBase[11];
};

__device__ __forceinline__ void ld8(float* d, const float* p){
  float4 v0 = *(const float4*)p;
  float4 v1 = *(const float4*)(p + 4);
  d[0]=v0.x; d[1]=v0.y; d[2]=v0.z; d[3]=v0.w;
  d[4]=v1.x; d[5]=v1.y; d[6]=v1.z; d[7]=v1.w;
}

__device__ __forceinline__ void cvt_hilo(const float* A, f16x8& H, f16x8& L){
  _Float16 hh[8], ll[8];
  #pragma unroll
  for (int j = 0; j < 8; ++j){
    _Float16 h = (_Float16)A[j];
    hh[j] = h;
    ll[j] = (_Float16)(A[j] - (float)h);
  }
  H = *(f16x8*)hh; L = *(f16x8*)ll;
}

__launch_bounds__(256, 4)
__global__ void gemm_kernel(GemmArgs a){
  // XCD-aware swizzle (grid % 8 == 0): consecutive logical WGs (same-B m-tiles)
  // land on the same XCD's L2.
  int nx = (int)gridDim.x >> 3;
  int bid = ((int)blockIdx.x & 7) * nx + ((int)blockIdx.x >> 3);

  int g = 0;
  while (bid >= a.wgBase[g+1]) ++g;
  int loc = bid - a.wgBase[g];
  int mt = loc & 15;       // 16 m-tiles (1024/64)
  int ks = loc >> 4;
  int nch = a.nch[g], ksp = a.ksplit[g];
  int q = nch / ksp, r = nch % ksp;
  int c0  = ks * q + (ks < r ? ks : r);
  int cnt = q + (ks < r ? 1 : 0);

  const float* X = a.X[g];
  int K = a.K[g];
  const unsigned short* Wh = a.Wh[g];

  int t = threadIdx.x;
  int lane = t & 63, w = t >> 6;
  int ln15 = lane & 15, kg = lane >> 4;
  int rowbase = mt * 64;
  // lane's A base for fragment i=0: row (rowbase+ln15), k-offset kg*8
  const float* xr = X + (size_t)(rowbase + ln15) * K + kg * 8;
  const size_t rstep = (size_t)16 * K;   // fragment i -> i*16 rows down

  f32x4 acc[4][4];
  #pragma unroll
  for (int i = 0; i < 4; ++i)
    #pragma unroll
    for (int j = 0; j < 4; ++j) acc[i][j] = (f32x4){0.f,0.f,0.f,0.f};

  for (int ci = 0; ci < cnt; ++ci){
    int c = c0 + ci;
    int k0 = c * 32;
    // ---- B fragments (fp16 chunked, L2-resident across the 16 m-tiles) ----
    f16x8 bh[4];
    size_t cb = (size_t)c * (ND * 32);
    #pragma unroll
    for (int j = 0; j < 4; ++j)
      bh[j] = *(const f16x8*)(Wh + cb + (size_t)(w*64 + j*16 + ln15) * 32 + kg*8);
    // ---- A fragments straight from global (L1-shared across the 4 waves) ----
    float A0[8], A1[8], A2[8], A3[8];
    if (k0 + 32 <= K){               // wave-uniform fast path
      ld8(A0, xr + k0);
      ld8(A1, xr + k0 + rstep);
      ld8(A2, xr + k0 + 2*rstep);
      ld8(A3, xr + k0 + 3*rstep);
    } else {                         // only the final chunk of K=1000/500
      #pragma unroll
      for (int j = 0; j < 8; ++j){
        int k = k0 + kg*8 + j;
        bool ok = k < K;
        A0[j] = ok ? xr[k0 + j] : 0.f;
        A1[j] = ok ? xr[k0 + rstep + j] : 0.f;
        A2[j] = ok ? xr[k0 + 2*rstep + j] : 0.f;
        A3[j] = ok ? xr[k0 + 3*rstep + j] : 0.f;
      }
    }
    // ---- convert + MFMA (hi then lo per fragment) ----
    f16x8 H, L;
    cvt_hilo(A0, H, L);
    #pragma unroll
    for (int j = 0; j < 4; ++j){
      acc[0][j] = __builtin_amdgcn_mfma_f32_16x16x32_f16(H, bh[j], acc[0][j], 0, 0, 0);
      acc[0][j] = __builtin_amdgcn_mfma_f32_16x16x32_f16(L, bh[j], acc[0][j], 0, 0, 0);
    }
    cvt_hilo(A1, H, L);
    #pragma unroll
    for (int j = 0; j < 4; ++j){
      acc[1][j] = __builtin_amdgcn_mfma_f32_16x16x32_f16(H, bh[j], acc[1][j], 0, 0, 0);
      acc[1][j] = __builtin_amdgcn_mfma_f32_16x16x32_f16(L, bh[j], acc[1][j], 0, 0, 0);
    }
    cvt_hilo(A2, H, L);
    #pragma unroll
    for (int j = 0; j < 4; ++j){
      acc[2][j] = __builtin_amdgcn_mfma_f32_16x16x32_f16(H, bh[j], acc[2][j], 0, 0, 0);
      acc[2][j] = __builtin_amdgcn_mfma_f32_16x16x32_f16(L, bh[j], acc[2][j], 0, 0, 0);
    }
    cvt_hilo(A3, H, L);
    #pragma unroll
    for (int j = 0; j < 4; ++j){
      acc[3][j] = __builtin_amdgcn_mfma_f32_16x16x32_f16(H, bh[j], acc[3][j], 0, 0, 0);
      acc[3][j] = __builtin_amdgcn_mfma_f32_16x16x32_f16(L, bh[j], acc[3][j], 0, 0, 0);
    }
  }

  // ---- epilogue: atomic accumulate K-split partials ----
  float* C = a.C[g];
  int crow0 = kg * 4;
  #pragma unroll
  for (int i = 0; i < 4; ++i){
    #pragma unroll
    for (int j = 0; j < 4; ++j){
      int col = w*64 + j*16 + ln15;
      #pragma unroll
      for (int rr = 0; rr < 4; ++rr){
        int row = rowbase + i*16 + crow0 + rr;
        atomicAdd(&C[(size_t)row * ND + col], acc[i][j][rr]);
      }
    }
  }
}

// ---------------------------------------------------------------------------
// Kernel 4: fused homo-attention + hete routing + final softmax.
// One WG per batch row; wave f owns facet f; d = lane.
// ---------------------------------------------------------------------------
__device__ __forceinline__ float wsum(float v){
  #pragma unroll
  for (int m = 32; m; m >>= 1) v += __shfl_xor(v, m, 64);
  return v;
}

__global__ void fuse_kernel(const float* __restrict__ emb,
                            const float* __restrict__ homo_a,
                            float* __restrict__ out){
  int b = blockIdx.x;
  int t = threadIdx.x;
  int f = t >> 6;
  int d = t & 63;
  auto E = [&](int g){ return emb[((size_t)g * B_ROWS + b) * ND + t]; };

  float us = E(0), bs = E(1);
  float un[4], bn[4];
  #pragma unroll
  for (int i = 0; i < 4; ++i){ un[i] = E(2+i); bn[i] = E(6+i); }

  float ul[4], blv[4];
  #pragma unroll
  for (int i = 0; i < 4; ++i){
    float as_ = homo_a[i*128 + d],     an_ = homo_a[i*128 + 64 + d];
    float sc  = wsum(us*as_ + un[i]*an_);
    sc = sc > 0.f ? sc : 0.2f*sc;
    float alp = 1.f / (1.f + expf(-sc));
    ul[i] = us + alp*un[i];
    float as2 = homo_a[(4+i)*128 + d], an2 = homo_a[(4+i)*128 + 64 + d];
    float sc2 = wsum(bs*as2 + bn[i]*an2);
    sc2 = sc2 > 0.f ? sc2 : 0.2f*sc2;
    float alp2 = 1.f / (1.f + expf(-sc2));
    blv[i] = bs + alp2*bn[i];
  }

  float u0 = us / (sqrtf(wsum(us*us)) + 1e-8f);
  float zu[4], zb[4];
  #pragma unroll
  for (int i = 0; i < 4; ++i){
    zu[i] = ul[i]  / (sqrtf(wsum(ul[i]*ul[i]))   + 1e-8f);
    zb[i] = blv[i] / (sqrtf(wsum(blv[i]*blv[i])) + 1e-8f);
  }

  auto route = [&](float z0, float z1, float z2, float z3)->float{
    float u = u0;
    #pragma unroll
    for (int it = 0; it < 3; ++it){
      float d0 = wsum(u*z0), d1 = wsum(u*z1), d2 = wsum(u*z2), d3 = wsum(u*z3);
      float m = fmaxf(fmaxf(d0,d1), fmaxf(d2,d3));
      float e0 = expf(d0-m), e1 = expf(d1-m), e2 = expf(d2-m), e3 = expf(d3-m);
      float s = e0+e1+e2+e3;
      float nu = u0 + (e0*z0 + e1*z1 + e2*z2 + e3*z3) / s;
      u = nu / (sqrtf(wsum(nu*nu)) + 1e-8f);
    }
    return u;
  };

  float uu = route(zu[0], zu[1], zu[2], zu[3]);
  float ub = route(zb[0], zb[1], zb[2], zb[3]);

  float lg = wsum(uu*ub);
  __shared__ float sl[4];
  if (d == 0) sl[f] = lg;
  __syncthreads();
  if (t < 4){
    float l0 = sl[0], l1 = sl[1], l2 = sl[2], l3 = sl[3];
    float m = fmaxf(fmaxf(l0,l1), fmaxf(l2,l3));
    float den = expf(l0-m) + expf(l1-m) + expf(l2-m) + expf(l3-m);
    out[(size_t)b*4 + t] = expf(sl[t]-m) / den;
  }
}

// ---------------------------------------------------------------------------
extern "C" void kernel_launch(void* const* d_in, const int* in_sizes, int n_in,
                              void* d_out, int out_size, void* d_ws, size_t ws_size,
                              hipStream_t stream) {
  const float* X[10];
  for (int i = 0; i < 10; ++i) X[i] = (const float*)d_in[i];
  const float* Wm[4]   = { (const float*)d_in[10], (const float*)d_in[12],
                           (const float*)d_in[14], (const float*)d_in[16] };
  const float* bias[4] = { (const float*)d_in[11], (const float*)d_in[13],
                           (const float*)d_in[15], (const float*)d_in[17] };
  const float* homo_a  = (const float*)d_in[18];
  float* out = (float*)d_out;

  // workspace: emb (10.5 MB) + fp16 W chunks (21.3 MB) ~ 32 MB total
  const size_t EMB_FLOATS = 10ull * B_ROWS * ND;
  float* emb = (float*)d_ws;
  unsigned short* wch = (unsigned short*)((char*)d_ws + EMB_FLOATS * 4);
  const int nchW[4] = {625, 625, 32, 16};   // ceil(K/32)
  const int Kw[4]   = {20000, 20000, 1000, 500};
  size_t off[4];
  {
    size_t o = 0;
    for (int w = 0; w < 4; ++w){ off[w] = o; o += (size_t)nchW[w] * ND * 32; }
  }

  // ---- conv W (fp32 -> fp16 chunked) ----
  ConvArgs ca;
  int cbase = 0;
  for (int w = 0; w < 4; ++w){
    ca.W[w] = Wm[w];
    ca.dst[w] = wch + off[w];
    ca.K[w] = Kw[w];
    ca.chBase[w] = cbase;
    cbase += nchW[w];
  }
  hipLaunchKernelGGL(conv_w_kernel, dim3(cbase), dim3(256), 0, stream, ca);

  // ---- bias init ----
  static const int biasOf[10] = {0,1,0,1,2,3,0,1,2,3};
  BiasArgs ba;
  ba.emb = emb;
  for (int g = 0; g < 10; ++g) ba.b[g] = bias[biasOf[g]];
  hipLaunchKernelGGL(bias_init_kernel, dim3((EMB_FLOATS/4)/256), dim3(256), 0, stream, ba);

  // ---- gemm: grid = 16 m-tiles x ksplit per group = 1056 WGs (div by 8) ----
  static const int wOf[10] = {0,1,0,1,2,3,0,1,2,3};
  static const int ksp[10] = {10,10,10,10,2,1,10,10,2,1};
  GemmArgs ga;
  int base = 0;
  for (int g = 0; g < 10; ++g){
    ga.X[g]  = X[g];
    ga.Wh[g] = wch + off[wOf[g]];
    ga.C[g]  = emb + (size_t)g * B_ROWS * ND;
    ga.K[g]  = Kw[wOf[g]];
    ga.nch[g] = nchW[wOf[g]];
    ga.ksplit[g] = ksp[g];
    ga.wgBase[g] = base;
    base += 16 * ksp[g];
  }
  ga.wgBase[10] = base;   // 1056
  hipLaunchKernelGGL(gemm_kernel, dim3(base), dim3(256), 0, stream, ga);

  // ---- fused attention/routing ----
  hipLaunchKernelGGL(fuse_kernel, dim3(B_ROWS), dim3(256), 0, stream, emb, homo_a, out);
}

// Round 5
// 561.802 us; speedup vs baseline: 1.3799x; 1.3799x over previous
//
#include <hip/hip_runtime.h>
#include <hip/hip_bf16.h>
#include <stdint.h>
#include <stddef.h>

typedef __attribute__((ext_vector_type(8))) _Float16 f16x8;
typedef __attribute__((ext_vector_type(4))) float f32x4;

#define B_ROWS 1024
#define ND 256

// ---------------------------------------------------------------------------
// Kernel 1: convert W (fp32 [K][256]) -> fp16 RTN, chunked [c][256][32] so
// MFMA B-fragments are contiguous 16B runs. Fully-coalesced global reads.
// ---------------------------------------------------------------------------
struct ConvArgs {
  const float* W[4];
  unsigned short* dst[4];
  int K[4];
  int chBase[4];
};

__global__ void conv_w_kernel(ConvArgs a){
  int cb = blockIdx.x;
  int w = 0;
  if (cb >= a.chBase[1]) w = 1;
  if (cb >= a.chBase[2]) w = 2;
  if (cb >= a.chBase[3]) w = 3;
  int c = cb - a.chBase[w];
  __shared__ float tile[32][257];
  const float* Wp = a.W[w];
  int K = a.K[w];
  int t = threadIdx.x;
  const float* src = Wp + (size_t)c * 32 * ND;
  bool full = (c * 32 + 32 <= K);
  #pragma unroll
  for (int j = 0; j < 8; ++j){
    int idx = j * 256 + t;          // float4 index in 32x256 block
    int row = idx >> 6;
    int col = (idx & 63) * 4;
    float4 v;
    if (full || (c * 32 + row < K)) v = *(const float4*)(src + (size_t)idx * 4);
    else { v.x = v.y = v.z = v.w = 0.f; }
    tile[row][col+0] = v.x; tile[row][col+1] = v.y;
    tile[row][col+2] = v.z; tile[row][col+3] = v.w;
  }
  __syncthreads();
  int n = t;
  union { unsigned short s[32]; uint4 v[4]; } pk;
  #pragma unroll
  for (int k = 0; k < 32; ++k){
    _Float16 h = (_Float16)tile[k][n];                  // RTN
    pk.s[k] = *(unsigned short*)&h;
  }
  unsigned short* d = a.dst[w] + ((size_t)c * ND + n) * 32;
  #pragma unroll
  for (int q = 0; q < 4; ++q) *(uint4*)(d + q*8) = pk.v[q];
}

// ---------------------------------------------------------------------------
// Kernel 2: init the 10 embedding buffers with biases (GEMM atomics accumulate).
// ---------------------------------------------------------------------------
struct BiasArgs { float* emb; const float* b[10]; };

__global__ void bias_init_kernel(BiasArgs a){
  int idx = blockIdx.x * blockDim.x + threadIdx.x;
  int g  = idx >> 16;
  int wi = idx & 65535;
  int n4 = (wi & 63) * 4;
  const float* bp = a.b[g];
  float4 v; v.x = bp[n4]; v.y = bp[n4+1]; v.z = bp[n4+2]; v.w = bp[n4+3];
  *(float4*)(a.emb + (size_t)idx * 4) = v;
}

// ---------------------------------------------------------------------------
// Kernel 3: pipelined 2-term fp16-split MFMA GEMM.  C[g] += X[g] @ fp16(W[g]).
// ONE __syncthreads per chunk (at top); all loads issued right after it and
// consumed late -> latency hidden under 32 MFMAs (T14 async-split).
// LDS: double-buffered [2][64][32]-half hi/lo, conflict-free read AND write.
// A converted fp32->fp16 hi/lo ONCE per element at stage time.
// ---------------------------------------------------------------------------
struct GemmArgs {
  const float* X[10];
  const unsigned short* Wh[10];
  float* C[10];
  int K[10];
  int nch[10];
  int ksplit[10];
  int wgBase[11];
};

__launch_bounds__(256, 4)
__global__ void gemm_kernel(GemmArgs a){
  __shared__ _Float16 Ahi[2][64][32];   // 4KB each buffer
  __shared__ _Float16 Alo[2][64][32];

  // XCD-aware swizzle (grid % 8 == 0)
  int nx = (int)gridDim.x >> 3;
  int bid = ((int)blockIdx.x & 7) * nx + ((int)blockIdx.x >> 3);

  int g = 0;
  while (bid >= a.wgBase[g+1]) ++g;
  int loc = bid - a.wgBase[g];
  int mt = loc & 15;       // 16 m-tiles (1024/64)
  int ks = loc >> 4;
  int nch = a.nch[g], ksp = a.ksplit[g];
  int q = nch / ksp, r = nch % ksp;
  int c0  = ks * q + (ks < r ? ks : r);
  int cnt = q + (ks < r ? 1 : 0);

  const float* X = a.X[g];
  int K = a.K[g];
  const unsigned short* Wh = a.Wh[g];

  int t = threadIdx.x;
  int lane = t & 63, w = t >> 6;
  int ln15 = lane & 15, kg = lane >> 4;
  int rowbase = mt * 64;

  // staging assignment: thread t stages row (t>>2), k-granule (t&3) = 8 floats
  int srow = t >> 2, skg = t & 3;
  const float* xsrc = X + (size_t)(rowbase + srow) * K + skg * 8;

  f32x4 acc[4][4];
  #pragma unroll
  for (int i = 0; i < 4; ++i)
    #pragma unroll
    for (int j = 0; j < 4; ++j) acc[i][j] = (f32x4){0.f,0.f,0.f,0.f};

  // guarded 8-float row-segment load (tail chunks of K=1000/500 only)
  auto ldA = [&](float* d, int c){
    int k0 = c * 32 + skg * 8;
    if (k0 + 8 <= K){
      float4 v0 = *(const float4*)(xsrc + c*32);
      float4 v1 = *(const float4*)(xsrc + c*32 + 4);
      d[0]=v0.x; d[1]=v0.y; d[2]=v0.z; d[3]=v0.w;
      d[4]=v1.x; d[5]=v1.y; d[6]=v1.z; d[7]=v1.w;
    } else {
      for (int j = 0; j < 8; ++j) d[j] = (k0 + j < K) ? xsrc[c*32 + j] : 0.f;
    }
  };
  // convert + conflict-free ds_write (hi,lo 16B granules)
  auto stA = [&](int buf, const float* v){
    _Float16 hh[8], ll[8];
    #pragma unroll
    for (int j = 0; j < 8; ++j){
      _Float16 h = (_Float16)v[j];
      hh[j] = h;
      ll[j] = (_Float16)(v[j] - (float)h);
    }
    *(f16x8*)&Ahi[buf][srow][skg*8] = *(f16x8*)hh;
    *(f16x8*)&Alo[buf][srow][skg*8] = *(f16x8*)ll;
  };

  // prologue: stage chunk c0 into buffer 0
  {
    float v[8];
    ldA(v, c0);
    stA(0, v);
  }

  for (int ci = 0; ci < cnt; ++ci){
    int c = c0 + ci;
    int cur = ci & 1;
    __syncthreads();                    // buf[cur] = chunk c ready (drain is free:
                                        // nothing issued since last consumption)
    // ---- issue ALL loads for this iteration right after the barrier ----
    f16x8 bh[4];                        // B of chunk c (L2-resident, used mid-compute)
    size_t cb = (size_t)c * (ND * 32);
    #pragma unroll
    for (int j = 0; j < 4; ++j)
      bh[j] = *(const f16x8*)(Wh + cb + (size_t)(w*64 + j*16 + ln15) * 32 + kg*8);
    float v[8];                         // X of chunk c+1 (HBM, used at end)
    bool pre = (ci + 1 < cnt);
    if (pre) ldA(v, c + 1);
    // ---- compute chunk c from buf[cur] ----
    #pragma unroll
    for (int i = 0; i < 4; ++i){
      f16x8 ah = *(const f16x8*)&Ahi[cur][i*16 + ln15][kg*8];
      f16x8 al = *(const f16x8*)&Alo[cur][i*16 + ln15][kg*8];
      #pragma unroll
      for (int j = 0; j < 4; ++j){
        acc[i][j] = __builtin_amdgcn_mfma_f32_16x16x32_f16(ah, bh[j], acc[i][j], 0, 0, 0);
        acc[i][j] = __builtin_amdgcn_mfma_f32_16x16x32_f16(al, bh[j], acc[i][j], 0, 0, 0);
      }
    }
    // ---- convert+write chunk c+1 into the other buffer (no barrier needed:
    //      its previous readers finished before this iteration's barrier) ----
    if (pre) stA(cur ^ 1, v);
  }

  // ---- epilogue: atomic accumulate K-split partials ----
  float* C = a.C[g];
  int crow0 = kg * 4;
  #pragma unroll
  for (int i = 0; i < 4; ++i){
    #pragma unroll
    for (int j = 0; j < 4; ++j){
      int col = w*64 + j*16 + ln15;
      #pragma unroll
      for (int rr = 0; rr < 4; ++rr){
        int row = rowbase + i*16 + crow0 + rr;
        atomicAdd(&C[(size_t)row * ND + col], acc[i][j][rr]);
      }
    }
  }
}

// ---------------------------------------------------------------------------
// Kernel 4: fused homo-attention + hete routing + final softmax.
// One WG per batch row; wave f owns facet f; d = lane.
// ---------------------------------------------------------------------------
__device__ __forceinline__ float wsum(float v){
  #pragma unroll
  for (int m = 32; m; m >>= 1) v += __shfl_xor(v, m, 64);
  return v;
}

__global__ void fuse_kernel(const float* __restrict__ emb,
                            const float* __restrict__ homo_a,
                            float* __restrict__ out){
  int b = blockIdx.x;
  int t = threadIdx.x;
  int f = t >> 6;
  int d = t & 63;
  auto E = [&](int g){ return emb[((size_t)g * B_ROWS + b) * ND + t]; };

  float us = E(0), bs = E(1);
  float un[4], bn[4];
  #pragma unroll
  for (int i = 0; i < 4; ++i){ un[i] = E(2+i); bn[i] = E(6+i); }

  float ul[4], blv[4];
  #pragma unroll
  for (int i = 0; i < 4; ++i){
    float as_ = homo_a[i*128 + d],     an_ = homo_a[i*128 + 64 + d];
    float sc  = wsum(us*as_ + un[i]*an_);
    sc = sc > 0.f ? sc : 0.2f*sc;
    float alp = 1.f / (1.f + expf(-sc));
    ul[i] = us + alp*un[i];
    float as2 = homo_a[(4+i)*128 + d], an2 = homo_a[(4+i)*128 + 64 + d];
    float sc2 = wsum(bs*as2 + bn[i]*an2);
    sc2 = sc2 > 0.f ? sc2 : 0.2f*sc2;
    float alp2 = 1.f / (1.f + expf(-sc2));
    blv[i] = bs + alp2*bn[i];
  }

  float u0 = us / (sqrtf(wsum(us*us)) + 1e-8f);
  float zu[4], zb[4];
  #pragma unroll
  for (int i = 0; i < 4; ++i){
    zu[i] = ul[i]  / (sqrtf(wsum(ul[i]*ul[i]))   + 1e-8f);
    zb[i] = blv[i] / (sqrtf(wsum(blv[i]*blv[i])) + 1e-8f);
  }

  auto route = [&](float z0, float z1, float z2, float z3)->float{
    float u = u0;
    #pragma unroll
    for (int it = 0; it < 3; ++it){
      float d0 = wsum(u*z0), d1 = wsum(u*z1), d2 = wsum(u*z2), d3 = wsum(u*z3);
      float m = fmaxf(fmaxf(d0,d1), fmaxf(d2,d3));
      float e0 = expf(d0-m), e1 = expf(d1-m), e2 = expf(d2-m), e3 = expf(d3-m);
      float s = e0+e1+e2+e3;
      float nu = u0 + (e0*z0 + e1*z1 + e2*z2 + e3*z3) / s;
      u = nu / (sqrtf(wsum(nu*nu)) + 1e-8f);
    }
    return u;
  };

  float uu = route(zu[0], zu[1], zu[2], zu[3]);
  float ub = route(zb[0], zb[1], zb[2], zb[3]);

  float lg = wsum(uu*ub);
  __shared__ float sl[4];
  if (d == 0) sl[f] = lg;
  __syncthreads();
  if (t < 4){
    float l0 = sl[0], l1 = sl[1], l2 = sl[2], l3 = sl[3];
    float m = fmaxf(fmaxf(l0,l1), fmaxf(l2,l3));
    float den = expf(l0-m) + expf(l1-m) + expf(l2-m) + expf(l3-m);
    out[(size_t)b*4 + t] = expf(sl[t]-m) / den;
  }
}

// ---------------------------------------------------------------------------
extern "C" void kernel_launch(void* const* d_in, const int* in_sizes, int n_in,
                              void* d_out, int out_size, void* d_ws, size_t ws_size,
                              hipStream_t stream) {
  const float* X[10];
  for (int i = 0; i < 10; ++i) X[i] = (const float*)d_in[i];
  const float* Wm[4]   = { (const float*)d_in[10], (const float*)d_in[12],
                           (const float*)d_in[14], (const float*)d_in[16] };
  const float* bias[4] = { (const float*)d_in[11], (const float*)d_in[13],
                           (const float*)d_in[15], (const float*)d_in[17] };
  const float* homo_a  = (const float*)d_in[18];
  float* out = (float*)d_out;

  const size_t EMB_FLOATS = 10ull * B_ROWS * ND;
  float* emb = (float*)d_ws;
  unsigned short* wch = (unsigned short*)((char*)d_ws + EMB_FLOATS * 4);
  const int nchW[4] = {625, 625, 32, 16};   // ceil(K/32)
  const int Kw[4]   = {20000, 20000, 1000, 500};
  size_t off[4];
  {
    size_t o = 0;
    for (int w = 0; w < 4; ++w){ off[w] = o; o += (size_t)nchW[w] * ND * 32; }
  }

  // ---- conv W (fp32 -> fp16 chunked) ----
  ConvArgs ca;
  int cbase = 0;
  for (int w = 0; w < 4; ++w){
    ca.W[w] = Wm[w];
    ca.dst[w] = wch + off[w];
    ca.K[w] = Kw[w];
    ca.chBase[w] = cbase;
    cbase += nchW[w];
  }
  hipLaunchKernelGGL(conv_w_kernel, dim3(cbase), dim3(256), 0, stream, ca);

  // ---- bias init ----
  static const int biasOf[10] = {0,1,0,1,2,3,0,1,2,3};
  BiasArgs ba;
  ba.emb = emb;
  for (int g = 0; g < 10; ++g) ba.b[g] = bias[biasOf[g]];
  hipLaunchKernelGGL(bias_init_kernel, dim3((EMB_FLOATS/4)/256), dim3(256), 0, stream, ba);

  // ---- gemm: grid = 16 m-tiles x Σksp = 768 WGs = 256 CU x 3..4 resident ----
  static const int wOf[10] = {0,1,0,1,2,3,0,1,2,3};
  static const int ksp[10] = {7,7,7,7,2,1,7,7,2,1};
  GemmArgs ga;
  int base = 0;
  for (int g = 0; g < 10; ++g){
    ga.X[g]  = X[g];
    ga.Wh[g] = wch + off[wOf[g]];
    ga.C[g]  = emb + (size_t)g * B_ROWS * ND;
    ga.K[g]  = Kw[wOf[g]];
    ga.nch[g] = nchW[wOf[g]];
    ga.ksplit[g] = ksp[g];
    ga.wgBase[g] = base;
    base += 16 * ksp[g];
  }
  ga.wgBase[10] = base;   // 768
  hipLaunchKernelGGL(gemm_kernel, dim3(base), dim3(256), 0, stream, ga);

  // ---- fused attention/routing ----
  hipLaunchKernelGGL(fuse_kernel, dim3(B_ROWS), dim3(256), 0, stream, emb, homo_a, out);
}